// Round 12
// baseline (56.666 us; speedup 1.0000x reference)
//
#include <hip/hip_runtime.h>

typedef unsigned long long u64;
typedef unsigned int u32;

#define BATCH 64
#define CH    64
#define HH    56
#define WW    56
#define HW    3136
#define SROW  64            // padded Spk row stride (u64)
#define SIMG  (58 * SROW)   // per-image u64 count (58 rows incl pads)
#define PBLK  1792          // pack blocks: 2 w-halves x 896 (4 rows each)

// Kernel 1: pack sign bits into zero-padded [b][58][64] + weight/BN fold.
//  blk < PBLK : rowblk = blk>>1 (4 rows, one per wave), half = blk&1 (w 0-27 / 28-55).
//               lane = channel; ballot-pack; lanes 0..27 hold u64 for w = half*28+lane.
//  blk >= PBLK: p = blk-PBLK -> wtab record (9 bit-words + {-2am,al,b2}) + kc table.
__global__ __launch_bounds__(256)
void pack_kernel(const float* __restrict__ x,
                 const float* __restrict__ bias0,
                 const float* __restrict__ w,
                 const float* __restrict__ gamma,
                 const float* __restrict__ beta,
                 const float* __restrict__ rmean,
                 const float* __restrict__ rvar,
                 const float* __restrict__ bias1,
                 const float* __restrict__ alpha,
                 const float* __restrict__ bias2,
                 u64* __restrict__ Spk,
                 u64* __restrict__ wtab,      // [64][12]
                 float* __restrict__ kc) {    // [9][64]
    const int tid = threadIdx.x;
    const int lane = tid & 63;
    const int wv = tid >> 6;
    const int blk = blockIdx.x;

    if (blk < PBLK) {
        const int half = blk & 1;
        const int w0 = half * 28;
        const int row = (blk >> 1) * 4 + wv;     // = b*56 + h
        const int b = row / HH;
        const int h = row - b * HH;
        const float* xp = x + ((size_t)(b * CH + lane)) * HW + h * WW + w0;
        const float bz = bias0[lane];
        u64 mine = 0;
#pragma unroll
        for (int q = 0; q < 7; ++q) {
            float4 v = *(const float4*)(xp + q * 4);   // 16B aligned (w0=0 or 28)
            u64 m0 = __ballot(v.x + bz > 0.f);
            u64 m1 = __ballot(v.y + bz > 0.f);
            u64 m2 = __ballot(v.z + bz > 0.f);
            u64 m3 = __ballot(v.w + bz > 0.f);
            mine = (lane == q * 4 + 0) ? m0 : mine;
            mine = (lane == q * 4 + 1) ? m1 : mine;
            mine = (lane == q * 4 + 2) ? m2 : mine;
            mine = (lane == q * 4 + 3) ? m3 : mine;
        }
        u64* sp = Spk + (size_t)b * SIMG + (h + 1) * SROW;
        if (lane < 28) sp[1 + w0 + lane] = mine;
        // col pads
        if (half == 0 && lane == 28) sp[0] = 0;
        if (half == 1 && lane == 28) sp[57] = 0;
        // row pads (each half zeroes its 29 entries)
        if (h == 0 && lane >= 29 && lane < 58)
            Spk[(size_t)b * SIMG + half * 29 + (lane - 29)] = 0;
        if (h == HH - 1 && lane >= 29 && lane < 58)
            Spk[(size_t)b * SIMG + 57 * SROW + half * 29 + (lane - 29)] = 0;
    } else {
        __shared__ float red[4];
        const int p = blk - PBLK;
        const float* wp = w + p * 576;
        float s = 0.f;
        for (int i = tid; i < 576; i += 256) s += fabsf(wp[i]);
#pragma unroll
        for (int off = 32; off > 0; off >>= 1) s += __shfl_down(s, off);
        if (lane == 0) red[wv] = s;
        __syncthreads();

        if (wv == 0) {
            u64 m[9];
#pragma unroll
            for (int t = 0; t < 9; ++t) {
                m[t] = __ballot(wp[lane * 9 + t] > 0.f);   // bit c = sign(w[p][c][t])
                if (lane == 0) wtab[p * 12 + t] = m[t];
            }
            if (lane == 0) {
                float scale = (red[0] + red[1] + red[2] + red[3]) * (1.0f / 576.0f);
                float inv = gamma[p] * rsqrtf(rvar[p] + 1e-5f);
                float am = scale * inv;
                float bd = beta[p] - rmean[p] * inv + bias1[p];
                float pt[9];
#pragma unroll
                for (int t = 0; t < 9; ++t) pt[t] = (float)__popcll(m[t]);
                const float cL = pt[0] + pt[3] + pt[6];
                const float cR = pt[2] + pt[5] + pt[8];
                const float rT = pt[0] + pt[1] + pt[2];
                const float rB = pt[6] + pt[7] + pt[8];
                float Ci[3][3] = {
                    {0.f, cL,                 cR},
                    {rT,  rT + pt[3] + pt[6], rT + pt[5] + pt[8]},
                    {rB,  rB + pt[0] + pt[3], rB + pt[2] + pt[5]}};
                float nv[3][3] = {{9, 6, 6}, {6, 4, 4}, {6, 4, 4}};
#pragma unroll
                for (int wc = 0; wc < 3; ++wc)
#pragma unroll
                    for (int lc = 0; lc < 3; ++lc)
                        kc[(wc * 3 + lc) * 64 + p] =
                            fmaf(am, 64.f * nv[wc][lc] + 2.f * Ci[wc][lc], bd);
                float* cf = (float*)(wtab + p * 12 + 9);
                cf[0] = -2.f * am;
                cf[1] = alpha[p];
                cf[2] = bias2[p];
                cf[3] = 0.f;
                wtab[p * 12 + 11] = 0;
            }
        }
    }
}

// Kernel 2: XNOR-popcount conv + fused BN/residual/PReLU epilogue.
// Grid 3584 blocks (one row each, 8*448 XCD swizzle) x 256 thr (4 waves).
// Wave wv: channels wv*16..+15 of its row; lane = w pixel.
// A-words from padded Spk (9 unconditional coalesced u64 loads);
// weights/consts via wave-uniform s_load records; res double-buffered 8-deep.
__global__ __launch_bounds__(256, 8)
void conv_kernel(const u64* __restrict__ Spk,
                 const u64* __restrict__ wtab,
                 const float* __restrict__ kc,
                 const float* __restrict__ x,
                 float* __restrict__ out) {
    __shared__ __align__(16) float kcsm[576];
    const int tid = threadIdx.x;
    for (int i = tid; i < 576; i += 256) kcsm[i] = kc[i];
    __syncthreads();

    const int bid = blockIdx.x;
    const int wg = (bid & 7) * 448 + (bid >> 3);      // bijective: 3584 = 8*448
    const int lane = tid & 63;
    const int ph = __builtin_amdgcn_readfirstlane((tid >> 6) << 4);  // 0,16,32,48
    const int b = wg / HH;
    const int h = wg - b * HH;
    const int wl = min(lane, WW - 1);
    const bool active = lane < WW;

    // 9 tap words (zero pads: unconditional), pinned in VGPRs
    const u64* ap = Spk + (size_t)b * SIMG + (h + 1) * SROW + (wl + 1);
    u64 A0 = ap[-SROW - 1], A1 = ap[-SROW], A2 = ap[-SROW + 1];
    u64 A3 = ap[-1],        A4 = ap[0],     A5 = ap[1];
    u64 A6 = ap[SROW - 1],  A7 = ap[SROW],  A8 = ap[SROW + 1];
    asm volatile("" : "+v"(A0), "+v"(A1), "+v"(A2), "+v"(A3), "+v"(A4),
                      "+v"(A5), "+v"(A6), "+v"(A7), "+v"(A8));

    const int wclass = (h == 0) ? 1 : (h == HH - 1) ? 2 : 0;
    const int lclass = (lane == 0) ? 1 : (lane == WW - 1) ? 2 : 0;
    const float* kp = kcsm + (wclass * 3 + lclass) * 64 + ph;

    const u32 base = (u32)(b * CH * HW + h * WW + wl) + (u32)ph * HW;

    // 2 chunks x 8 channels, 1-chunk-ahead residual prefetch (R11-validated)
    float res[2][8];
#pragma unroll
    for (int j = 0; j < 8; ++j) res[0][j] = x[base + (u32)j * HW];
#pragma unroll
    for (int j = 0; j < 8; ++j) asm volatile("" : "+v"(res[0][j]));

#pragma unroll
    for (int c = 0; c < 2; ++c) {
        if (c < 1) {
#pragma unroll
            for (int j = 0; j < 8; ++j)
                res[1][j] = x[base + (u32)(8 + j) * HW];
#pragma unroll
            for (int j = 0; j < 8; ++j) asm volatile("" : "+v"(res[1][j]));
        }
        float4 k0 = *(const float4*)(kp + c * 8);
        float4 k1 = *(const float4*)(kp + c * 8 + 4);
        float kv[8] = {k0.x, k0.y, k0.z, k0.w, k1.x, k1.y, k1.z, k1.w};

#pragma unroll
        for (int j = 0; j < 8; ++j) {
            const u64* wp = wtab + (ph + c * 8 + j) * 12;   // uniform -> s_load
            u32 P = 0;
            u64 v;
            v = A0 ^ wp[0]; P += __popc((u32)v); P += __popc((u32)(v >> 32));
            v = A1 ^ wp[1]; P += __popc((u32)v); P += __popc((u32)(v >> 32));
            v = A2 ^ wp[2]; P += __popc((u32)v); P += __popc((u32)(v >> 32));
            v = A3 ^ wp[3]; P += __popc((u32)v); P += __popc((u32)(v >> 32));
            v = A4 ^ wp[4]; P += __popc((u32)v); P += __popc((u32)(v >> 32));
            v = A5 ^ wp[5]; P += __popc((u32)v); P += __popc((u32)(v >> 32));
            v = A6 ^ wp[6]; P += __popc((u32)v); P += __popc((u32)(v >> 32));
            v = A7 ^ wp[7]; P += __popc((u32)v); P += __popc((u32)(v >> 32));
            v = A8 ^ wp[8]; P += __popc((u32)v); P += __popc((u32)(v >> 32));

            const float* cf = (const float*)(wp + 9);   // {-2am, al, b2}
            float o = fmaf(cf[0], (float)P, kv[j]) + res[c][j];
            o = o >= 0.f ? o : cf[1] * o;
            o += cf[2];
            if (active) out[base + (u32)(c * 8 + j) * HW] = o;
        }
    }
}

extern "C" void kernel_launch(void* const* d_in, const int* in_sizes, int n_in,
                              void* d_out, int out_size, void* d_ws, size_t ws_size,
                              hipStream_t stream) {
    const float* x     = (const float*)d_in[0];
    const float* bias0 = (const float*)d_in[1];
    const float* w     = (const float*)d_in[2];
    const float* gamma = (const float*)d_in[3];
    const float* beta  = (const float*)d_in[4];
    const float* rmean = (const float*)d_in[5];
    const float* rvar  = (const float*)d_in[6];
    const float* bias1 = (const float*)d_in[7];
    const float* alpha = (const float*)d_in[8];
    const float* bias2 = (const float*)d_in[9];
    float* out = (float*)d_out;

    char* ws = (char*)d_ws;
    u64* wtab = (u64*)ws;                  // 64*12*8 = 6,144 B
    float* kc = (float*)(ws + 6144);       // 9*64*4  = 2,304 B
    u64* Spk  = (u64*)(ws + 16384);        // 64*58*64*8 = 1,900,544 B

    pack_kernel<<<PBLK + 64, 256, 0, stream>>>(
        x, bias0, w, gamma, beta, rmean, rvar, bias1, alpha, bias2,
        Spk, wtab, kc);

    conv_kernel<<<BATCH * HH, 256, 0, stream>>>(Spk, wtab, kc, x, out);
}